// Round 4
// baseline (2268.296 us; speedup 1.0000x reference)
//
#include <hip/hip_runtime.h>
#include <stdint.h>

#define BB    4096   // batch
#define Z1D   128
#define CD    12     // cond dim
#define HD    1024   // hidden
#define TT    32     // steps
#define N3H   3072   // 3*HD
#define KAUG  1056   // 1024 h + 12 feed + 20 pad = 33*32
#define NPH0  1152   // ceil(1024/192)*192 padded N for h0 GEMM

typedef __bf16 bf16;
typedef __bf16 bf16x8 __attribute__((ext_vector_type(8)));
typedef float  f32x4  __attribute__((ext_vector_type(4)));
typedef float  f4     __attribute__((ext_vector_type(4)));

typedef const __attribute__((address_space(1))) void* as1cv;
typedef __attribute__((address_space(3))) void* as3v;

__device__ __forceinline__ float sigm(float x){ return 1.0f/(1.0f+__expf(-x)); }
__device__ __forceinline__ float tanhfast(float x){ return 1.0f - 2.0f/(1.0f+__expf(2.0f*x)); }

// interleaved column index n' -> original gate row (g*1024 + jn)
__device__ __forceinline__ int rowOfN(int np, int& g){
  int jb = np/192; int r = np - jb*192; g = r>>6; int jl = r&63;
  return g*1024 + jb*64 + jl;
}

// ---------------- prep: weight conversion / layout / zero-init ----------------
__global__ __launch_bounds__(256)
void prep_k(const float* __restrict__ z, const float* __restrict__ Wih,
            const float* __restrict__ Whh, const float* __restrict__ bih,
            const float* __restrict__ bhh, const float* __restrict__ Winit,
            bf16* __restrict__ Wg, bf16* __restrict__ Wz, bf16* __restrict__ Wi0,
            bf16* __restrict__ zbf, float* __restrict__ biasz, float* __restrict__ bhhn,
            bf16* __restrict__ A0, bf16* __restrict__ A1)
{
  const int N1 = N3H*KAUG;        // Wg
  const int N2 = N3H*Z1D;         // Wz
  const int N3 = NPH0*Z1D;        // Wi0
  const int N4 = BB*Z1D;          // zbf
  const int N5 = N3H;             // biasz
  const int N6 = HD;              // bhhn
  const int N7 = 2*BB*KAUG;       // zero A0/A1
  int idx = blockIdx.x*256 + threadIdx.x;
  if (idx < N1){
    int np = idx/KAUG, k = idx - np*KAUG;
    int g; int row = rowOfN(np, g);
    float v = 0.0f;
    if (k < 1024) v = Whh[(size_t)row*HD + k];
    else if (k < 1036 && g < 2) v = Wih[(size_t)row*140 + (k-1024)];
    Wg[idx] = (bf16)v;
    return;
  }
  idx -= N1;
  if (idx < N2){
    int np = idx/Z1D, kk = idx - np*Z1D;
    int g; int row = rowOfN(np, g);
    Wz[idx] = (bf16)Wih[(size_t)row*140 + 12 + kk];
    return;
  }
  idx -= N2;
  if (idx < N3){
    int jn = idx/Z1D, kk = idx - jn*Z1D;
    Wi0[idx] = (jn < HD) ? (bf16)Winit[(size_t)jn*Z1D + kk] : (bf16)0.0f;
    return;
  }
  idx -= N3;
  if (idx < N4){ zbf[idx] = (bf16)z[idx]; return; }
  idx -= N4;
  if (idx < N5){
    int g; int row = rowOfN(idx, g);
    biasz[idx] = bih[row] + (g < 2 ? bhh[row] : 0.0f);
    return;
  }
  idx -= N5;
  if (idx < N6){ bhhn[idx] = bhh[2048 + idx]; return; }
  idx -= N6;
  if (idx < N7){
    if (idx < BB*KAUG) A0[idx] = (bf16)0.0f;
    else               A1[idx - BB*KAUG] = (bf16)0.0f;
  }
}

// ---------------- GEMM: C[M,N'] = A[M,K] @ Bw[N',K]^T, fused epilogues ----------------
// EP 0 = ZP   (write fp32 acc+biasz)
// EP 1 = H0   (tanh(acc+b_init) -> hprev fp32 + A0 bf16)
// EP 2 = GATES (full GRU cell update)
template<int EP>
__global__ __launch_bounds__(256, 2)
void gemm_k(const bf16* __restrict__ A, int lda,
            const bf16* __restrict__ Bw, int ldb, int ksteps,
            const float* __restrict__ zp, const float* __restrict__ biasz,
            const float* __restrict__ bias1, const float* __restrict__ bhhn,
            const float* __restrict__ Wih, const float* __restrict__ cond,
            const float* __restrict__ hprev, float* __restrict__ hnext,
            const bf16* __restrict__ Acur, bf16* __restrict__ Anext,
            float* __restrict__ outf, int t)
{
  __shared__ bf16 lA[128*32];
  __shared__ bf16 lB[192*32];
  const int tid = threadIdx.x, wid = tid>>6, lane = tid&63;
  const int l15 = lane&15, l4 = lane>>4;
  const int n0 = blockIdx.x*192, m0 = blockIdx.y*128;

  f32x4 acc[2][12];
  #pragma unroll
  for (int i=0;i<2;++i)
    #pragma unroll
    for (int j=0;j<12;++j) acc[i][j] = (f32x4){0.f,0.f,0.f,0.f};

  for (int ks=0; ks<ksteps; ++ks){
    const int k0 = ks*32;
    __syncthreads();
    {
      const bf16* gA = A + (size_t)m0*lda + k0;
      #pragma unroll
      for (int r=0; r<2; ++r){
        int q = r*256 + tid;               // 16B chunk id; 4 chunks per 32-elem row
        int row = q>>2, kk = (q&3)*8;
        const bf16* gp = gA + (size_t)row*lda + kk;
        bf16* lp = &lA[(size_t)(r*256 + wid*64)*8];
        __builtin_amdgcn_global_load_lds((as1cv)gp, (as3v)lp, 16, 0, 0);
      }
      const bf16* gB = Bw + (size_t)n0*ldb + k0;
      #pragma unroll
      for (int r=0; r<3; ++r){
        int q = r*256 + tid;
        int row = q>>2, kk = (q&3)*8;
        const bf16* gp = gB + (size_t)row*ldb + kk;
        bf16* lp = &lB[(size_t)(r*256 + wid*64)*8];
        __builtin_amdgcn_global_load_lds((as1cv)gp, (as3v)lp, 16, 0, 0);
      }
    }
    __syncthreads();
    bf16x8 af0 = *(const bf16x8*)&lA[(wid*32 +  0 + l15)*32 + l4*8];
    bf16x8 af1 = *(const bf16x8*)&lA[(wid*32 + 16 + l15)*32 + l4*8];
    #pragma unroll
    for (int cf=0; cf<12; ++cf){
      bf16x8 bfr = *(const bf16x8*)&lB[(cf*16 + l15)*32 + l4*8];
      acc[0][cf] = __builtin_amdgcn_mfma_f32_16x16x32_bf16(af0, bfr, acc[0][cf], 0,0,0);
      acc[1][cf] = __builtin_amdgcn_mfma_f32_16x16x32_bf16(af1, bfr, acc[1][cf], 0,0,0);
    }
  }

  const int rbase = m0 + wid*32 + l4*4;

  if constexpr (EP == 0){
    #pragma unroll
    for (int rf=0; rf<2; ++rf)
      #pragma unroll
      for (int cf=0; cf<12; ++cf){
        int np = n0 + cf*16 + l15;
        float bz = biasz[np];
        #pragma unroll
        for (int reg=0; reg<4; ++reg){
          int b = rbase + rf*16 + reg;
          outf[(size_t)b*N3H + np] = acc[rf][cf][reg] + bz;
        }
      }
  }
  else if constexpr (EP == 1){
    #pragma unroll
    for (int rf=0; rf<2; ++rf)
      #pragma unroll
      for (int cf=0; cf<12; ++cf){
        int jn = n0 + cf*16 + l15;
        if (jn < HD){
          float bi = bias1[jn];
          #pragma unroll
          for (int reg=0; reg<4; ++reg){
            int b = rbase + rf*16 + reg;
            float h = tanhfast(acc[rf][cf][reg] + bi);
            hnext[(size_t)b*HD + jn] = h;
            Anext[(size_t)b*KAUG + jn] = (bf16)h;
          }
        }
      }
  }
  else {  // EP == 2: GRU gates
    const int jblk = blockIdx.x;
    // n-gate feed weights: W_ih[2048+jn, 0:12], per jf (shared across rf/reg)
    float wfn[4][12];
    #pragma unroll
    for (int jf=0; jf<4; ++jf){
      int jn = jblk*64 + jf*16 + l15;
      const f4* wr = (const f4*)(Wih + (size_t)(2048 + jn)*140);
      f4 w0 = wr[0], w1 = wr[1], w2 = wr[2];
      #pragma unroll
      for (int c=0;c<4;++c){ wfn[jf][c]=w0[c]; wfn[jf][4+c]=w1[c]; wfn[jf][8+c]=w2[c]; }
    }
    #pragma unroll
    for (int rf=0; rf<2; ++rf){
      #pragma unroll
      for (int reg=0; reg<4; ++reg){
        int b = rbase + rf*16 + reg;
        // feed vector for this row (bf16, cols 1024:1036 of A_cur)
        const bf16* fr = Acur + (size_t)b*KAUG + 1024;
        bf16x8 f8 = *(const bf16x8*)fr;
        float fd[12];
        #pragma unroll
        for (int c=0;c<8;++c) fd[c] = (float)f8[c];
        #pragma unroll
        for (int c=8;c<12;++c) fd[c] = (float)fr[c];
        #pragma unroll
        for (int jf=0; jf<4; ++jf){
          int jn = jblk*64 + jf*16 + l15;
          size_t zb = (size_t)b*N3H + n0 + jf*16 + l15;
          float aR = acc[rf][jf  ][reg] + zp[zb];
          float aZ = acc[rf][4+jf][reg] + zp[zb+64];
          float iN = zp[zb+128];
          float hN = acc[rf][8+jf][reg] + bhhn[jn];
          float fdot = 0.0f;
          #pragma unroll
          for (int c=0;c<12;++c) fdot += fd[c]*wfn[jf][c];
          float r = sigm(aR);
          float u = sigm(aZ);
          float nn = tanhfast(iN + fdot + r*hN);
          float hp = hprev[(size_t)b*HD + jn];
          float hv = (1.0f-u)*nn + u*hp;
          hnext[(size_t)b*HD + jn] = hv;
          Anext[(size_t)b*KAUG + jn] = (bf16)hv;
        }
      }
    }
    // feed columns of A_next for step t+1 : condition[:, t, :]
    if (jblk == 0){
      for (int i = tid; i < 128*CD; i += 256){
        int rr = i/CD, c = i - rr*CD;
        int b = m0 + rr;
        Anext[(size_t)b*KAUG + 1024 + c] = (bf16)cond[((size_t)b*TT + t)*CD + c];
      }
    }
  }
}

// ---------------- output projection: x_t = sigmoid(h @ W_out^T + b_out) ----------------
__global__ __launch_bounds__(256)
void out_k(const float* __restrict__ h, const float* __restrict__ Wout,
           const float* __restrict__ bout, float* __restrict__ out, int t)
{
  __shared__ float sw[CD*HD];
  __shared__ float sb[CD];
  const int tid = threadIdx.x;
  for (int i=tid; i<CD*HD; i+=256) sw[i] = Wout[i];
  if (tid < CD) sb[tid] = bout[tid];
  __syncthreads();
  const int wid = tid>>6, lane = tid&63;
  const int b0 = blockIdx.x*16 + wid*4;
  for (int rr=0; rr<4; ++rr){
    int b = b0 + rr;
    const float* hr = h + (size_t)b*HD;
    float p[CD];
    #pragma unroll
    for (int c=0;c<CD;++c) p[c] = 0.0f;
    #pragma unroll
    for (int j=0;j<16;++j){
      float hv = hr[lane + j*64];
      #pragma unroll
      for (int c=0;c<CD;++c) p[c] += hv*sw[c*HD + lane + j*64];
    }
    #pragma unroll
    for (int c=0;c<CD;++c){
      float v = p[c];
      #pragma unroll
      for (int m=32;m>=1;m>>=1) v += __shfl_xor(v, m, 64);
      if (lane == 0) out[((size_t)b*TT + t)*CD + c] = sigm(v + sb[c]);
    }
  }
}

// ---------------- launch ----------------
extern "C" void kernel_launch(void* const* d_in, const int* in_sizes, int n_in,
                              void* d_out, int out_size, void* d_ws, size_t ws_size,
                              hipStream_t stream) {
  const float* z     = (const float*)d_in[0];
  const float* cond  = (const float*)d_in[1];
  const float* Wih   = (const float*)d_in[3];
  const float* Whh   = (const float*)d_in[4];
  const float* bih   = (const float*)d_in[5];
  const float* bhh   = (const float*)d_in[6];
  const float* Winit = (const float*)d_in[7];
  const float* binit = (const float*)d_in[8];
  const float* Wout  = (const float*)d_in[9];
  const float* bout  = (const float*)d_in[10];
  float* out = (float*)d_out;

  char* ws = (char*)d_ws;
  size_t off = 0;
  auto carve = [&](size_t bytes)->char*{
    char* p = ws + off; off += (bytes + 255) & ~(size_t)255; return p;
  };
  bf16*  Wg    = (bf16*) carve((size_t)N3H*KAUG*2);
  bf16*  Wz    = (bf16*) carve((size_t)N3H*Z1D*2);
  bf16*  Wi0   = (bf16*) carve((size_t)NPH0*Z1D*2);
  bf16*  zbf   = (bf16*) carve((size_t)BB*Z1D*2);
  float* biasz = (float*)carve((size_t)N3H*4);
  float* bhhn  = (float*)carve((size_t)HD*4);
  float* zpl   = (float*)carve((size_t)BB*N3H*4);
  bf16*  A0    = (bf16*) carve((size_t)BB*KAUG*2);
  bf16*  A1    = (bf16*) carve((size_t)BB*KAUG*2);
  float* hp0   = (float*)carve((size_t)BB*HD*4);
  float* hp1   = (float*)carve((size_t)BB*HD*4);

  // prep
  {
    int total = N3H*KAUG + N3H*Z1D + NPH0*Z1D + BB*Z1D + N3H + HD + 2*BB*KAUG;
    int blocks = (total + 255)/256;
    prep_k<<<blocks, 256, 0, stream>>>(z, Wih, Whh, bih, bhh, Winit,
                                       Wg, Wz, Wi0, zbf, biasz, bhhn, A0, A1);
  }
  // z_proj (interleaved layout) : M=4096, N=3072, K=128
  gemm_k<0><<<dim3(16,32), 256, 0, stream>>>(zbf, Z1D, Wz, Z1D, 4,
      nullptr, biasz, nullptr, nullptr, nullptr, nullptr,
      nullptr, nullptr, nullptr, nullptr, zpl, 0);
  // h0 : M=4096, N=1024(pad 1152), K=128
  gemm_k<1><<<dim3(6,32), 256, 0, stream>>>(zbf, Z1D, Wi0, Z1D, 4,
      nullptr, nullptr, binit, nullptr, nullptr, nullptr,
      nullptr, hp0, nullptr, A0, nullptr, 0);

  for (int t = 0; t < TT; ++t){
    const bf16*  Ac = (t & 1) ? A1 : A0;
    bf16*        An = (t & 1) ? A0 : A1;
    const float* hc = (t & 1) ? hp1 : hp0;
    float*       hn = (t & 1) ? hp0 : hp1;
    gemm_k<2><<<dim3(16,32), 256, 0, stream>>>(Ac, KAUG, Wg, KAUG, 33,
        zpl, nullptr, nullptr, bhhn, Wih, cond,
        hc, hn, Ac, An, nullptr, t);
    out_k<<<256, 256, 0, stream>>>(hn, Wout, bout, out, t);
  }
}

// Round 5
// 2194.700 us; speedup vs baseline: 1.0335x; 1.0335x over previous
//
#include <hip/hip_runtime.h>
#include <stdint.h>

#define BB    4096   // batch
#define Z1D   128
#define CD    12     // cond dim
#define HD    1024   // hidden
#define TT    32     // steps
#define N3H   3072   // 3*HD
#define KAUG  1056   // 1024 h + 12 feed + 20 pad = 33*32
#define NPH0  1056   // ceil(1024/96)*96 padded N for h0 GEMM

typedef __bf16 bf16;
typedef __bf16 bf16x2 __attribute__((ext_vector_type(2)));
typedef __bf16 bf16x8 __attribute__((ext_vector_type(8)));
typedef float  f32x4  __attribute__((ext_vector_type(4)));
typedef float  f4     __attribute__((ext_vector_type(4)));

typedef const __attribute__((address_space(1))) void* as1cv;
typedef __attribute__((address_space(3))) void* as3v;

__device__ __forceinline__ float sigm(float x){ return 1.0f/(1.0f+__expf(-x)); }
__device__ __forceinline__ float tanhfast(float x){ return 1.0f - 2.0f/(1.0f+__expf(2.0f*x)); }

// interleaved column index n' -> original gate row (g*1024 + jn)
// 96-wide blocks: [r(32) | z(32) | n(32)] for 32 consecutive hidden cols
__device__ __forceinline__ int rowOfN(int np, int& g){
  int jb = np/96; int r = np - jb*96; g = r>>5; int jl = r&31;
  return g*1024 + jb*32 + jl;
}

// ---------------- prep: weight conversion / layout / zero-init ----------------
__global__ __launch_bounds__(256)
void prep_k(const float* __restrict__ z, const float* __restrict__ Wih,
            const float* __restrict__ Whh, const float* __restrict__ bih,
            const float* __restrict__ bhh, const float* __restrict__ Winit,
            bf16* __restrict__ Wg, bf16* __restrict__ Wz, bf16* __restrict__ Wi0,
            bf16* __restrict__ zbf, float* __restrict__ biasz, float* __restrict__ bhhn,
            bf16* __restrict__ A0, bf16* __restrict__ A1)
{
  const int N1 = N3H*KAUG;        // Wg
  const int N2 = N3H*Z1D;        // Wz
  const int N3 = NPH0*Z1D;       // Wi0
  const int N4 = BB*Z1D;         // zbf
  const int N5 = N3H;            // biasz
  const int N6 = HD;             // bhhn
  const int N7 = 2*BB*KAUG;      // zero A0/A1
  int idx = blockIdx.x*256 + threadIdx.x;
  if (idx < N1){
    int np = idx/KAUG, k = idx - np*KAUG;
    int g; int row = rowOfN(np, g);
    float v = 0.0f;
    if (k < 1024) v = Whh[(size_t)row*HD + k];
    else if (k < 1036 && g < 2) v = Wih[(size_t)row*140 + (k-1024)];
    Wg[idx] = (bf16)v;
    return;
  }
  idx -= N1;
  if (idx < N2){
    int np = idx/Z1D, kk = idx - np*Z1D;
    int g; int row = rowOfN(np, g);
    Wz[idx] = (bf16)Wih[(size_t)row*140 + 12 + kk];
    return;
  }
  idx -= N2;
  if (idx < N3){
    int jn = idx/Z1D, kk = idx - jn*Z1D;
    Wi0[idx] = (jn < HD) ? (bf16)Winit[(size_t)jn*Z1D + kk] : (bf16)0.0f;
    return;
  }
  idx -= N3;
  if (idx < N4){ zbf[idx] = (bf16)z[idx]; return; }
  idx -= N4;
  if (idx < N5){
    int g; int row = rowOfN(idx, g);
    biasz[idx] = bih[row] + (g < 2 ? bhh[row] : 0.0f);
    return;
  }
  idx -= N5;
  if (idx < N6){ bhhn[idx] = bhh[2048 + idx]; return; }
  idx -= N6;
  if (idx < N7){
    if (idx < BB*KAUG) A0[idx] = (bf16)0.0f;
    else               A1[idx - BB*KAUG] = (bf16)0.0f;
  }
}

// ---------------- GEMM: C[M,N'] = A[M,K] @ Bw[N',K]^T, fused epilogues ----------------
// Tile 128x96, 4 waves, wave = 32 rows x 96 cols (acc[2][6]); double-buffered LDS,
// prefetch next K-tile before computing current (one barrier per K-step).
// EP 0 = ZP (write fp32 acc+biasz) | EP 1 = H0 (tanh->h0) | EP 2 = GATES (GRU cell)
template<int EP>
__global__ __launch_bounds__(256, 4)
void gemm_k(const bf16* __restrict__ A, int lda,
            const bf16* __restrict__ Bw, int ldb, int ksteps,
            const float* __restrict__ zp, const float* __restrict__ biasz,
            const float* __restrict__ bias1, const float* __restrict__ bhhn,
            const float* __restrict__ Wih, const float* __restrict__ cond,
            const float* __restrict__ hprev, float* __restrict__ hnext,
            const bf16* __restrict__ Acur, bf16* __restrict__ Anext,
            float* __restrict__ outf, int t)
{
  __shared__ bf16 lA[2][128*32];
  __shared__ bf16 lB[2][96*32];
  const int tid = threadIdx.x, wid = tid>>6, lane = tid&63;
  const int l15 = lane&15, l4 = lane>>4;

  int bx, by;
  if constexpr (EP == 2){
    // XCD-aware bijective swizzle over 1024 blocks (nwg%8==0)
    int bid = blockIdx.x;
    int swz = (bid&7)*128 + (bid>>3);
    bx = swz>>5; by = swz&31;
  } else {
    bx = blockIdx.x; by = blockIdx.y;
  }
  const int n0 = bx*96, m0 = by*128;

  f32x4 acc[2][6];
  #pragma unroll
  for (int i=0;i<2;++i)
    #pragma unroll
    for (int j=0;j<6;++j) acc[i][j] = (f32x4){0.f,0.f,0.f,0.f};

  // stage K-tile ks into buffer buf
  auto STAGE = [&](int buf, int ks){
    const int k0 = ks*32;
    const bf16* gA = A + (size_t)m0*lda + k0;
    #pragma unroll
    for (int r=0; r<2; ++r){
      int q = r*256 + tid;               // 16B chunk id; 4 chunks per 32-elem row
      const bf16* gp = gA + (size_t)(q>>2)*lda + (q&3)*8;
      bf16* lp = &lA[buf][(size_t)(r*256 + wid*64)*8];
      __builtin_amdgcn_global_load_lds((as1cv)gp, (as3v)lp, 16, 0, 0);
    }
    const bf16* gB = Bw + (size_t)n0*ldb + k0;
    {
      int q = tid;
      const bf16* gp = gB + (size_t)(q>>2)*ldb + (q&3)*8;
      bf16* lp = &lB[buf][(size_t)(wid*64)*8];
      __builtin_amdgcn_global_load_lds((as1cv)gp, (as3v)lp, 16, 0, 0);
    }
    if (tid < 128){                      // rows 64..95 (waves 0,1 fully active)
      int q = 256 + tid;
      const bf16* gp = gB + (size_t)(q>>2)*ldb + (q&3)*8;
      bf16* lp = &lB[buf][(size_t)(256 + wid*64)*8];
      __builtin_amdgcn_global_load_lds((as1cv)gp, (as3v)lp, 16, 0, 0);
    }
  };

  int cur = 0;
  STAGE(0, 0);
  for (int ks=0; ks<ksteps; ++ks){
    __syncthreads();                     // drains vmcnt -> buf[cur] ready, prev reads done
    if (ks+1 < ksteps) STAGE(cur^1, ks+1);
    bf16x8 af0 = *(const bf16x8*)&lA[cur][(wid*32 +  0 + l15)*32 + l4*8];
    bf16x8 af1 = *(const bf16x8*)&lA[cur][(wid*32 + 16 + l15)*32 + l4*8];
    #pragma unroll
    for (int cf=0; cf<6; ++cf){
      bf16x8 bfr = *(const bf16x8*)&lB[cur][(cf*16 + l15)*32 + l4*8];
      acc[0][cf] = __builtin_amdgcn_mfma_f32_16x16x32_bf16(af0, bfr, acc[0][cf], 0,0,0);
      acc[1][cf] = __builtin_amdgcn_mfma_f32_16x16x32_bf16(af1, bfr, acc[1][cf], 0,0,0);
    }
    cur ^= 1;
  }

  const int rbase = m0 + wid*32 + l4*4;

  if constexpr (EP == 0){
    #pragma unroll
    for (int rf=0; rf<2; ++rf)
      #pragma unroll
      for (int cf=0; cf<6; ++cf){
        int np = n0 + cf*16 + l15;
        float bz = biasz[np];
        #pragma unroll
        for (int reg=0; reg<4; ++reg){
          int b = rbase + rf*16 + reg;
          outf[(size_t)b*N3H + np] = acc[rf][cf][reg] + bz;
        }
      }
  }
  else if constexpr (EP == 1){
    #pragma unroll
    for (int rf=0; rf<2; ++rf)
      #pragma unroll
      for (int cf=0; cf<6; ++cf){
        int jn = n0 + cf*16 + l15;
        if (jn < HD){
          float bi = bias1[jn];
          #pragma unroll
          for (int reg=0; reg<4; ++reg){
            int b = rbase + rf*16 + reg;
            float h = tanhfast(acc[rf][cf][reg] + bi);
            hnext[(size_t)b*HD + jn] = h;
            Anext[(size_t)b*KAUG + jn] = (bf16)h;
          }
        }
      }
  }
  else {  // EP == 2: GRU gates
    const int jblk = bx;
    // n-gate feed weights: W_ih[2048+jn, 0:12]
    float wfn[2][12];
    #pragma unroll
    for (int jf=0; jf<2; ++jf){
      int jn = jblk*32 + jf*16 + l15;
      const f4* wr = (const f4*)(Wih + (size_t)(2048 + jn)*140);
      f4 w0 = wr[0], w1 = wr[1], w2 = wr[2];
      #pragma unroll
      for (int c=0;c<4;++c){ wfn[jf][c]=w0[c]; wfn[jf][4+c]=w1[c]; wfn[jf][8+c]=w2[c]; }
    }
    #pragma unroll
    for (int rf=0; rf<2; ++rf){
      #pragma unroll
      for (int reg=0; reg<4; ++reg){
        int b = rbase + rf*16 + reg;
        // feed vector for this row (bf16, cols 1024:1036 of A_cur)
        const bf16* fr = Acur + (size_t)b*KAUG + 1024;
        bf16x8 f8 = *(const bf16x8*)fr;
        float fd[12];
        #pragma unroll
        for (int c=0;c<8;++c) fd[c] = (float)f8[c];
        #pragma unroll
        for (int c=8;c<12;++c) fd[c] = (float)fr[c];
        #pragma unroll
        for (int jf=0; jf<2; ++jf){
          int jn = jblk*32 + jf*16 + l15;
          size_t zb = (size_t)b*N3H + n0 + jf*16 + l15;
          float aR = acc[rf][jf  ][reg] + zp[zb];
          float aZ = acc[rf][2+jf][reg] + zp[zb+32];
          float iN = zp[zb+64];
          float hN = acc[rf][4+jf][reg] + bhhn[jn];
          float fdot = 0.0f;
          #pragma unroll
          for (int c=0;c<12;++c) fdot += fd[c]*wfn[jf][c];
          float r = sigm(aR);
          float u = sigm(aZ);
          float nn = tanhfast(iN + fdot + r*hN);
          float hp = hprev[(size_t)b*HD + jn];
          float hv = (1.0f-u)*nn + u*hp;
          hnext[(size_t)b*HD + jn] = hv;
          Anext[(size_t)b*KAUG + jn] = (bf16)hv;
        }
      }
    }
    // feed columns of A_next for step t+1 : condition[:, t, :]
    if (jblk == 0){
      for (int i = tid; i < 128*CD; i += 256){
        int rr = i/CD, c = i - rr*CD;
        int b = m0 + rr;
        Anext[(size_t)b*KAUG + 1024 + c] = (bf16)cond[((size_t)b*TT + t)*CD + c];
      }
    }
  }
}

// ---------------- output projection: x_t = sigmoid(h @ W_out^T + b_out) ----------------
// reads the bf16 state (cols 0:1024 of the A buffer)
__global__ __launch_bounds__(256)
void out_k(const bf16* __restrict__ hstate, const float* __restrict__ Wout,
           const float* __restrict__ bout, float* __restrict__ out, int t)
{
  __shared__ float sw[CD*HD];
  __shared__ float sb[CD];
  const int tid = threadIdx.x;
  for (int i=tid; i<CD*HD; i+=256) sw[i] = Wout[i];
  if (tid < CD) sb[tid] = bout[tid];
  __syncthreads();
  const int wid = tid>>6, lane = tid&63;
  const int b0 = blockIdx.x*16 + wid*4;
  for (int rr=0; rr<4; ++rr){
    int b = b0 + rr;
    const bf16* hr = hstate + (size_t)b*KAUG;
    float p[CD];
    #pragma unroll
    for (int c=0;c<CD;++c) p[c] = 0.0f;
    #pragma unroll
    for (int j=0;j<8;++j){
      int idx = lane*2 + j*128;
      bf16x2 hv = *(const bf16x2*)&hr[idx];
      float h0 = (float)hv[0], h1 = (float)hv[1];
      #pragma unroll
      for (int c=0;c<CD;++c) p[c] += h0*sw[c*HD + idx] + h1*sw[c*HD + idx + 1];
    }
    #pragma unroll
    for (int c=0;c<CD;++c){
      float v = p[c];
      #pragma unroll
      for (int m=32;m>=1;m>>=1) v += __shfl_xor(v, m, 64);
      if (lane == 0) out[((size_t)b*TT + t)*CD + c] = sigm(v + sb[c]);
    }
  }
}

// ---------------- launch ----------------
extern "C" void kernel_launch(void* const* d_in, const int* in_sizes, int n_in,
                              void* d_out, int out_size, void* d_ws, size_t ws_size,
                              hipStream_t stream) {
  const float* z     = (const float*)d_in[0];
  const float* cond  = (const float*)d_in[1];
  const float* Wih   = (const float*)d_in[3];
  const float* Whh   = (const float*)d_in[4];
  const float* bih   = (const float*)d_in[5];
  const float* bhh   = (const float*)d_in[6];
  const float* Winit = (const float*)d_in[7];
  const float* binit = (const float*)d_in[8];
  const float* Wout  = (const float*)d_in[9];
  const float* bout  = (const float*)d_in[10];
  float* out = (float*)d_out;

  char* ws = (char*)d_ws;
  size_t off = 0;
  auto carve = [&](size_t bytes)->char*{
    char* p = ws + off; off += (bytes + 255) & ~(size_t)255; return p;
  };
  bf16*  Wg    = (bf16*) carve((size_t)N3H*KAUG*2);
  bf16*  Wz    = (bf16*) carve((size_t)N3H*Z1D*2);
  bf16*  Wi0   = (bf16*) carve((size_t)NPH0*Z1D*2);
  bf16*  zbf   = (bf16*) carve((size_t)BB*Z1D*2);
  float* biasz = (float*)carve((size_t)N3H*4);
  float* bhhn  = (float*)carve((size_t)HD*4);
  float* zpl   = (float*)carve((size_t)BB*N3H*4);
  bf16*  A0    = (bf16*) carve((size_t)BB*KAUG*2);
  bf16*  A1    = (bf16*) carve((size_t)BB*KAUG*2);
  float* hp0   = (float*)carve((size_t)BB*HD*4);
  float* hp1   = (float*)carve((size_t)BB*HD*4);

  // prep
  {
    int total = N3H*KAUG + N3H*Z1D + NPH0*Z1D + BB*Z1D + N3H + HD + 2*BB*KAUG;
    int blocks = (total + 255)/256;
    prep_k<<<blocks, 256, 0, stream>>>(z, Wih, Whh, bih, bhh, Winit,
                                       Wg, Wz, Wi0, zbf, biasz, bhhn, A0, A1);
  }
  // z_proj (interleaved layout) : M=4096, N=3072, K=128
  gemm_k<0><<<dim3(32,32), 256, 0, stream>>>(zbf, Z1D, Wz, Z1D, 4,
      nullptr, biasz, nullptr, nullptr, nullptr, nullptr,
      nullptr, nullptr, nullptr, nullptr, zpl, 0);
  // h0 : M=4096, N=1024(pad 1056), K=128
  gemm_k<1><<<dim3(11,32), 256, 0, stream>>>(zbf, Z1D, Wi0, Z1D, 4,
      nullptr, nullptr, binit, nullptr, nullptr, nullptr,
      nullptr, hp0, nullptr, A0, nullptr, 0);

  for (int t = 0; t < TT; ++t){
    const bf16*  Ac = (t & 1) ? A1 : A0;
    bf16*        An = (t & 1) ? A0 : A1;
    const float* hc = (t & 1) ? hp1 : hp0;
    float*       hn = (t & 1) ? hp0 : hp1;
    gemm_k<2><<<1024, 256, 0, stream>>>(Ac, KAUG, Wg, KAUG, 33,
        zpl, nullptr, nullptr, bhhn, Wih, cond,
        hc, hn, Ac, An, nullptr, t);
    out_k<<<256, 256, 0, stream>>>(An, Wout, bout, out, t);
  }
}